// Round 1
// baseline (287.004 us; speedup 1.0000x reference)
//
#include <hip/hip_runtime.h>
#include <stdint.h>

// MinGRU fused pipeline:
//   1) ln_kernel:   x [BT,H] f32 -> normed [BT,H] bf16 (LayerNorm)
//   2) pack_kernel: Wg,Wc f32 -> wpack [2048,1024] bf16 (B^T layout, K-contig)
//   3) gemm_kernel: normed @ wpack^T + bias, sigmoid on first half
//                   -> zbuf, cbuf [BT,1024] bf16   (m97-style 128x128 tile MFMA)
//   4) scan1/scan2/scan3: chunked parallel linear recurrence + residual -> out f32

#define B_    4
#define T_    4096
#define H_    1024
#define BT_   (B_*T_)       // 16384
#define EPSV  1e-5f
#define CHK   32            // chunks over T
#define CL    (T_/CHK)      // 128 steps per chunk

typedef float  f32x4  __attribute__((ext_vector_type(4)));
typedef __bf16 bf16x8 __attribute__((ext_vector_type(8)));
typedef unsigned short u16;

__device__ __forceinline__ u16 f2bf(float f) {            // RNE f32->bf16
  uint32_t u = __builtin_bit_cast(uint32_t, f);
  u += 0x7fffu + ((u >> 16) & 1u);
  return (u16)(u >> 16);
}
__device__ __forceinline__ float bf2f(u16 u) {
  uint32_t v = ((uint32_t)u) << 16;
  return __builtin_bit_cast(float, v);
}

// ---------------- LayerNorm: one block per row ----------------
__global__ __launch_bounds__(256) void ln_kernel(
    const float* __restrict__ x, const float* __restrict__ gamma,
    const float* __restrict__ beta, u16* __restrict__ normed) {
  const int row = blockIdx.x;
  const int tid = threadIdx.x;
  const float4 v = reinterpret_cast<const float4*>(x + (size_t)row * H_)[tid];
  float s = v.x + v.y + v.z + v.w;
  float q = v.x*v.x + v.y*v.y + v.z*v.z + v.w*v.w;
  #pragma unroll
  for (int off = 32; off > 0; off >>= 1) {
    s += __shfl_down(s, off);
    q += __shfl_down(q, off);
  }
  __shared__ float ls[8], lq[8];
  const int wid = tid >> 6, lane = tid & 63;
  if (lane == 0) { ls[wid] = s; lq[wid] = q; }
  __syncthreads();
  if (tid == 0) {
    ls[4] = ls[0] + ls[1] + ls[2] + ls[3];
    lq[4] = lq[0] + lq[1] + lq[2] + lq[3];
  }
  __syncthreads();
  const float mean = ls[4] * (1.0f / H_);
  const float var  = lq[4] * (1.0f / H_) - mean * mean;
  const float rstd = rsqrtf(var + EPSV);
  const float4 g  = reinterpret_cast<const float4*>(gamma)[tid];
  const float4 bb = reinterpret_cast<const float4*>(beta)[tid];
  uint2 o;
  o.x = (uint32_t)f2bf((v.x - mean) * rstd * g.x + bb.x)
      | ((uint32_t)f2bf((v.y - mean) * rstd * g.y + bb.y) << 16);
  o.y = (uint32_t)f2bf((v.z - mean) * rstd * g.z + bb.z)
      | ((uint32_t)f2bf((v.w - mean) * rstd * g.w + bb.w) << 16);
  reinterpret_cast<uint2*>(normed + (size_t)row * H_)[tid] = o;
}

// ---------------- weight pack: [Wg;Wc] f32 -> bf16 [2048][1024] ----------------
__global__ __launch_bounds__(256) void pack_kernel(
    const float* __restrict__ Wg, const float* __restrict__ Wc,
    u16* __restrict__ wpack) {
  const int idx4 = (blockIdx.x * 256 + threadIdx.x) * 4;
  const int n = idx4 >> 10;
  const int k = idx4 & 1023;
  const float* src = (n < 1024) ? (Wg + (size_t)n * 1024 + k)
                                : (Wc + (size_t)(n - 1024) * 1024 + k);
  const float4 v = *reinterpret_cast<const float4*>(src);
  uint2 o;
  o.x = (uint32_t)f2bf(v.x) | ((uint32_t)f2bf(v.y) << 16);
  o.y = (uint32_t)f2bf(v.z) | ((uint32_t)f2bf(v.w) << 16);
  *reinterpret_cast<uint2*>(wpack + idx4) = o;
}

// ---------------- GEMM 128x128 tile, BK=32, 4 waves, global_load_lds w=16 ----
// out[bt][n] = sum_h normed[bt][h]*wpack[n][h];  n<1024 -> z=sigmoid(+bg) ; else c=+bc
__global__ __launch_bounds__(256) void gemm_kernel(
    const u16* __restrict__ A, const u16* __restrict__ Bw,
    const float* __restrict__ bg, const float* __restrict__ bc,
    u16* __restrict__ zbuf, u16* __restrict__ cbuf) {
  __shared__ u16 As[128 * 32];
  __shared__ u16 Bs[128 * 32];
  const int bid = blockIdx.x;
  const int nb  = (bid & 7) * 256 + (bid >> 3);   // XCD-aware swizzle (2048 % 8 == 0)
  const int mt  = nb >> 4, nt = nb & 15;
  const int tid = threadIdx.x;
  const int wid = tid >> 6, lane = tid & 63;
  const int wr = wid >> 1, wcq = wid & 1;

  f32x4 acc[4][4] = {};

  // staging: chunk c (16B = 8 bf16): row = c>>2, k8 = c&3; LDS linear at c*8 elems
  const int c0 = tid, c1 = tid + 256;
  const u16* a0 = A  + (size_t)(mt * 128 + (c0 >> 2)) * 1024 + (c0 & 3) * 8;
  const u16* a1 = A  + (size_t)(mt * 128 + (c1 >> 2)) * 1024 + (c1 & 3) * 8;
  const u16* b0 = Bw + (size_t)(nt * 128 + (c0 >> 2)) * 1024 + (c0 & 3) * 8;
  const u16* b1 = Bw + (size_t)(nt * 128 + (c1 >> 2)) * 1024 + (c1 & 3) * 8;

  const int frow = lane & 15;
  const int kb   = (lane >> 4) * 8;

  for (int ks = 0; ks < 32; ++ks) {
    const int kk = ks * 32;
    __builtin_amdgcn_global_load_lds(
        (const __attribute__((address_space(1))) void*)(a0 + kk),
        (__attribute__((address_space(3))) void*)&As[c0 * 8], 16, 0, 0);
    __builtin_amdgcn_global_load_lds(
        (const __attribute__((address_space(1))) void*)(a1 + kk),
        (__attribute__((address_space(3))) void*)&As[c1 * 8], 16, 0, 0);
    __builtin_amdgcn_global_load_lds(
        (const __attribute__((address_space(1))) void*)(b0 + kk),
        (__attribute__((address_space(3))) void*)&Bs[c0 * 8], 16, 0, 0);
    __builtin_amdgcn_global_load_lds(
        (const __attribute__((address_space(1))) void*)(b1 + kk),
        (__attribute__((address_space(3))) void*)&Bs[c1 * 8], 16, 0, 0);
    __syncthreads();   // drains vmcnt before any wave reads LDS

    bf16x8 af[4], bfr[4];
    #pragma unroll
    for (int m = 0; m < 4; ++m)
      af[m] = *reinterpret_cast<const bf16x8*>(&As[(wr * 64 + m * 16 + frow) * 32 + kb]);
    #pragma unroll
    for (int n = 0; n < 4; ++n)
      bfr[n] = *reinterpret_cast<const bf16x8*>(&Bs[(wcq * 64 + n * 16 + frow) * 32 + kb]);
    #pragma unroll
    for (int m = 0; m < 4; ++m)
      #pragma unroll
      for (int n = 0; n < 4; ++n)
        acc[m][n] = __builtin_amdgcn_mfma_f32_16x16x32_bf16(af[m], bfr[n], acc[m][n], 0, 0, 0);
    __syncthreads();   // protect LDS before next stage
  }

  // epilogue: C/D layout col = lane&15, row = (lane>>4)*4 + r  [m89]
  const int r0  = (lane >> 4) * 4;
  const int col16 = lane & 15;
  const bool isz = (nt < 8);   // block-uniform: whole tile is z-half or c-half
  #pragma unroll
  for (int m = 0; m < 4; ++m) {
    #pragma unroll
    for (int n = 0; n < 4; ++n) {
      const int col = nt * 128 + wcq * 64 + n * 16 + col16;
      #pragma unroll
      for (int r = 0; r < 4; ++r) {
        const int row = mt * 128 + wr * 64 + m * 16 + r0 + r;   // bt index
        float v = acc[m][n][r];
        if (isz) {
          v += bg[col];
          v = 1.0f / (1.0f + __expf(-v));
          zbuf[(size_t)row * 1024 + col] = f2bf(v);
        } else {
          const int cc = col - 1024;
          v += bc[cc];
          cbuf[(size_t)row * 1024 + cc] = f2bf(v);
        }
      }
    }
  }
}

// ---------------- scan phase 1: per-chunk (prod a, partial h with h_in=0) ----
__global__ __launch_bounds__(256) void scan1_kernel(
    const u16* __restrict__ zbuf, const u16* __restrict__ cbuf,
    float* __restrict__ Achk, float* __restrict__ Uchk) {
  const int bid   = blockIdx.x;
  const int o     = (bid & 3) * 256 + threadIdx.x;
  const int chunk = (bid >> 2) & 31;
  const int b     = bid >> 7;
  const size_t base = ((size_t)(b * T_ + chunk * CL)) * H_ + o;
  float A = 1.0f, u = 0.0f;
  #pragma unroll 8
  for (int t = 0; t < CL; ++t) {
    const float z = bf2f(zbuf[base + (size_t)t * H_]);
    const float c = bf2f(cbuf[base + (size_t)t * H_]);
    const float a = 1.0f - z;
    A *= a;
    u = a * u + z * c;
  }
  const int idx = (b * CHK + chunk) * H_ + o;
  Achk[idx] = A;
  Uchk[idx] = u;
}

// ---------------- scan phase 2: cross-chunk prefix (tiny) ----------------
__global__ __launch_bounds__(256) void scan2_kernel(
    const float* __restrict__ Achk, const float* __restrict__ Uchk,
    float* __restrict__ Hin) {
  const int bid = blockIdx.x;
  const int o   = (bid & 3) * 256 + threadIdx.x;
  const int b   = bid >> 2;
  float h = 0.0f;
  for (int j = 0; j < CHK; ++j) {
    const int idx = (b * CHK + j) * H_ + o;
    Hin[idx] = h;                       // h BEFORE chunk j
    h = Achk[idx] * h + Uchk[idx];
  }
}

// ---------------- scan phase 3: replay with h_in, add residual ----------------
__global__ __launch_bounds__(256) void scan3_kernel(
    const u16* __restrict__ zbuf, const u16* __restrict__ cbuf,
    const float* __restrict__ Hin, const float* __restrict__ x,
    float* __restrict__ out) {
  const int bid   = blockIdx.x;
  const int o     = (bid & 3) * 256 + threadIdx.x;
  const int chunk = (bid >> 2) & 31;
  const int b     = bid >> 7;
  float h = Hin[(b * CHK + chunk) * H_ + o];
  const size_t base = ((size_t)(b * T_ + chunk * CL)) * H_ + o;
  #pragma unroll 4
  for (int t = 0; t < CL; ++t) {
    const size_t idx = base + (size_t)t * H_;
    const float z = bf2f(zbuf[idx]);
    const float c = bf2f(cbuf[idx]);
    h = (1.0f - z) * h + z * c;
    out[idx] = h + x[idx];
  }
}

extern "C" void kernel_launch(void* const* d_in, const int* in_sizes, int n_in,
                              void* d_out, int out_size, void* d_ws, size_t ws_size,
                              hipStream_t stream) {
  const float* x     = (const float*)d_in[0];
  const float* gamma = (const float*)d_in[1];
  const float* beta  = (const float*)d_in[2];
  const float* Wg    = (const float*)d_in[3];
  const float* bg    = (const float*)d_in[4];
  const float* Wc    = (const float*)d_in[5];
  const float* bc    = (const float*)d_in[6];
  float* out = (float*)d_out;

  char* ws = (char*)d_ws;
  u16*   normed = (u16*)(ws);                         // 32 MB
  u16*   wpack  = (u16*)(ws + 33554432ull);           //  4 MB
  u16*   zbuf   = (u16*)(ws + 37748736ull);           // 32 MB
  u16*   cbuf   = (u16*)(ws + 71303168ull);           // 32 MB
  float* Achk   = (float*)(ws + 104857600ull);        // 0.5 MB
  float* Uchk   = (float*)(ws + 105381888ull);        // 0.5 MB
  float* Hin    = (float*)(ws + 105906176ull);        // 0.5 MB  (total ~101.5 MB)

  ln_kernel  <<<BT_,  256, 0, stream>>>(x, gamma, beta, normed);
  pack_kernel<<<2048, 256, 0, stream>>>(Wg, Wc, wpack);
  gemm_kernel<<<2048, 256, 0, stream>>>(normed, wpack, bg, bc, zbuf, cbuf);
  scan1_kernel<<<512, 256, 0, stream>>>(zbuf, cbuf, Achk, Uchk);
  scan2_kernel<<<16,  256, 0, stream>>>(Achk, Uchk, Hin);
  scan3_kernel<<<512, 256, 0, stream>>>(zbuf, cbuf, Hin, x, out);
}